// Round 1
// 329.294 us; speedup vs baseline: 1.0260x; 1.0260x over previous
//
#include <hip/hip_runtime.h>

#define NT 512
#define SEASN 24

constexpr int SEA_STRIDE = NT + SEASN;   // 536
constexpr int LOG_STRIDE = NT - 1;       // 511
constexpr float LN2 = 0.6931471805599453f;

constexpr int YS = 65;   // ybuf row stride (floats): (65l+k)%32=(l+k)%32 -> conflict-free
constexpr int TS = 33;   // sub-tile row stride: 32 cols + 1 boundary slot; (33l+k)%32=(l+k)%32

__device__ __forceinline__ float frcp(float x)  { return __builtin_amdgcn_rcpf(x); }
__device__ __forceinline__ float flog2(float x) { return __builtin_amdgcn_logf(x); }

// async global->LDS DMA: 4B/lane, dst = wave-uniform base + lane*4
__device__ __forceinline__ void gl_lds4(const float* g, float* lds) {
    __builtin_amdgcn_global_load_lds(
        (const __attribute__((address_space(1))) void*)g,
        (__attribute__((address_space(3))) void*)lds, 4, 0, 0);
}

// ---- compute wave: 32 recurrence steps, pure VALU + LDS (no global, no log) ----
template<int PHASE, bool FIRST>
__device__ __forceinline__ void compute_subtile(const float* __restrict__ yb,
                                                float* __restrict__ lt,
                                                float* __restrict__ st,
                                                float lsm, float (&buf)[SEASN],
                                                float& lev)
{
    float yp[32];                       // force all 32 y-reads issued up front
    #pragma unroll
    for (int k = 0; k < 32; ++k) yp[k] = yb[k];
    #pragma unroll
    for (int k = 0; k < 32; ++k) {
        const int pos = (PHASE + k) % SEASN;      // compile-time -> buf stays in VGPRs
        const float yt = yp[k];
        if (FIRST && k == 0) {
            lev = yt * frcp(buf[0]);              // lev0 = y0 / init_seas0
            lt[0] = lev;                          // levels[:,0]
            st[0] = buf[0];                       // seasonalities col 24
        } else {
            const float sv = buf[pos];
            const float nl = lev + lsm * (yt * frcp(sv) - lev);
            const float ns = sv + lsm * (yt * frcp(nl) - sv);   // seas_sms == lev_sms (ref sic)
            lt[k] = nl; st[k] = ns;
            lev = nl; buf[pos] = ns;
        }
    }
}

// ---- flusher wave: transpose-flush one 64x32 sub-tile, recompute log-diffs ----
__device__ __forceinline__ void flush_sub(const float* __restrict__ lt,
                                          const float* __restrict__ st,
                                          int sf, int q, int rr, int sbase,
                                          float* __restrict__ levels,
                                          float* __restrict__ seasv,
                                          float* __restrict__ logd)
{
    const int tb = sf * 32;
    #pragma unroll
    for (int i = 0; i < 8; ++i) {
        const int r = 8 * i + rr;                 // series row
        const size_t srow = (size_t)(sbase + r);
        const int off = r * TS + 4 * q;
        const float l0 = lt[off], l1 = lt[off+1], l2 = lt[off+2], l3 = lt[off+3];
        const float s0 = st[off], s1 = st[off+1], s2 = st[off+2], s3 = st[off+3];
        *(float4*)(levels + srow * NT + tb + 4*q)                  = make_float4(l0,l1,l2,l3);
        *(float4*)(seasv  + srow * SEA_STRIDE + SEASN + tb + 4*q)  = make_float4(s0,s1,s2,s3);
        // log-diffs recomputed here (moves flog2 off the serial wave)
        const float lm1 = (q == 0) ? lt[r * TS + 32] : lt[off - 1];   // sub-tile entry lev
        const float g0 = flog2(lm1), g1 = flog2(l0), g2 = flog2(l1),
                    g3 = flog2(l2),  g4 = flog2(l3);
        float* dp = logd + srow * LOG_STRIDE + tb + 4*q - 1;
        if (!(sf == 0 && q == 0)) dp[0] = (g1 - g0) * LN2;   // t=0 has no log-diff
        dp[1] = (g2 - g1) * LN2;
        dp[2] = (g3 - g2) * LN2;
        dp[3] = (g4 - g3) * LN2;
    }
}

__global__ __launch_bounds__(128)
void es_fwd(const float* __restrict__ y, const int* __restrict__ idxs,
            const float* __restrict__ lev_sms_p, const float* __restrict__ init_seas_p,
            float* __restrict__ levels, float* __restrict__ seasv,
            float* __restrict__ logd)
{
    __shared__ float ybuf[2][64 * YS];   // double-buffered y tiles (64 cols each)
    __shared__ float ltb [2][64 * TS];   // double-buffered level sub-tiles (32 cols)
    __shared__ float stb [2][64 * TS];   // double-buffered season sub-tiles   ~65.5 KB

    const int tid   = threadIdx.x;
    const int wid   = tid >> 6;          // 0 = compute wave, 1 = stage/flush wave
    const int lane  = tid & 63;
    const int sbase = blockIdx.x * 64;
    const int q  = lane & 7;             // time-quad within sub-tile
    const int rr = lane >> 3;            // series-row offset

    auto stage = [&](int T) {            // stage y tile T (64 cols, 256B dense per row)
        const float* g = y + (size_t)sbase * NT + T * 64 + lane;
        float* l = ybuf[T & 1];
        #pragma unroll
        for (int r = 0; r < 64; ++r)
            gl_lds4(g + (size_t)r * NT, l + r * YS);
    };

    float buf[SEASN];
    float lsm = 0.0f;
    float lev = 1.0f;

    if (wid == 0) {
        const int idx = idxs[sbase + lane];
        lsm = frcp(1.0f + __expf(-lev_sms_p[idx]));          // sigmoid
        const float4* is4 = (const float4*)(init_seas_p + (size_t)idx * SEASN);
        #pragma unroll
        for (int g4i = 0; g4i < 6; ++g4i) {
            float4 v = is4[g4i];
            buf[4*g4i+0] = __expf(v.x); buf[4*g4i+1] = __expf(v.y);
            buf[4*g4i+2] = __expf(v.z); buf[4*g4i+3] = __expf(v.w);
        }
        #pragma unroll
        for (int j = 0; j < SEASN; ++j)                      // stage init_seas for transpose
            ltb[1][lane * TS + j] = buf[j];
        asm volatile("s_waitcnt lgkmcnt(0)" ::: "memory");
    } else {
        stage(0);                                            // y tile 0
        asm volatile("s_waitcnt vmcnt(0)" ::: "memory");
    }
    __builtin_amdgcn_s_barrier();
    asm volatile("" ::: "memory");

    // 16 sub-tiles of 32 steps. Iter s: compute fills {ltb,stb}[s&1] from ybuf[(s>>1)&1]
    // while flusher stores sub-tile s-1 from the other buffer and DMAs the next y tile.
    for (int s = 0; s < 16; ++s) {
        if (wid == 0) {
            const float* yb = &ybuf[(s >> 1) & 1][lane * YS + (s & 1) * 32];
            float* lt = &ltb[s & 1][lane * TS];
            float* st = &stb[s & 1][lane * TS];
            lt[32] = lev;                                    // entry lev for flusher's dt
            const int ph = s % 3;                            // PHASE = (32s)%24 = 8*(s%3)
            if (s == 0)       compute_subtile<0,  true >(yb, lt, st, lsm, buf, lev);
            else if (ph == 0) compute_subtile<0,  false>(yb, lt, st, lsm, buf, lev);
            else if (ph == 1) compute_subtile<8,  false>(yb, lt, st, lsm, buf, lev);
            else              compute_subtile<16, false>(yb, lt, st, lsm, buf, lev);
            asm volatile("s_waitcnt lgkmcnt(0)" ::: "memory");   // tile visible at barrier
        } else {
            const int T = (s >> 1) + 1;
            if (!(s & 1) && T < 8) stage(T);                 // DMA next y tile (lead-2)
            if (s == 0) {
                // flush seasv cols 0..23 = exp(init_seas) transposed (from ltb[1])
                if (q < 6) {
                    #pragma unroll
                    for (int i = 0; i < 8; ++i) {
                        const int r = 8 * i + rr;
                        const int off = r * TS + 4 * q;
                        float4 v = make_float4(ltb[1][off],   ltb[1][off+1],
                                               ltb[1][off+2], ltb[1][off+3]);
                        *(float4*)(seasv + (size_t)(sbase + r) * SEA_STRIDE + 4 * q) = v;
                    }
                }
            } else {
                flush_sub(ltb[(s-1)&1], stb[(s-1)&1], s-1, q, rr, sbase,
                          levels, seasv, logd);
            }
            // counted wait: everything older than this iter's 48 flush stores is done
            // (guarantees DMA issued last iteration has landed; never drains stores to 0)
            asm volatile("s_waitcnt vmcnt(48)" ::: "memory");
        }
        __builtin_amdgcn_s_barrier();
        asm volatile("" ::: "memory");
    }
    if (wid == 1)                                            // epilogue: last sub-tile
        flush_sub(ltb[1], stb[1], 15, q, rr, sbase, levels, seasv, logd);
}

extern "C" void kernel_launch(void* const* d_in, const int* in_sizes, int n_in,
                              void* d_out, int out_size, void* d_ws, size_t ws_size,
                              hipStream_t stream)
{
    const float* y         = (const float*)d_in[0];
    const int*   idxs      = (const int*)d_in[1];
    const float* lev_sms   = (const float*)d_in[2];
    // d_in[3] (seas_sms) unused: reference derives both smoothings from lev_sms_p
    const float* init_seas = (const float*)d_in[4];
    const int n_series = in_sizes[1];

    float* levels = (float*)d_out;
    float* seasv  = levels + (size_t)n_series * NT;
    float* logdv  = seasv  + (size_t)n_series * SEA_STRIDE;

    es_fwd<<<n_series / 64, 128, 0, stream>>>(y, idxs, lev_sms, init_seas,
                                              levels, seasv, logdv);
}

// Round 2
// 309.309 us; speedup vs baseline: 1.0923x; 1.0646x over previous
//
#include <hip/hip_runtime.h>

#define NT 512
#define SEASN 24

constexpr int SEA_STRIDE = NT + SEASN;   // 536
constexpr int LOG_STRIDE = NT - 1;       // 511
constexpr float LN2 = 0.6931471805599453f;

constexpr int YS = 65;   // ybuf row stride: (65l+k)%32=(l+k)%32 -> 2-way = free
constexpr int TS = 33;   // sub-tile row stride: 32 cols + entry-lev slot
constexpr int NF = 4;    // flusher waves per block

__device__ __forceinline__ float frcp(float x)  { return __builtin_amdgcn_rcpf(x); }
__device__ __forceinline__ float flog2(float x) { return __builtin_amdgcn_logf(x); }

// async global->LDS DMA: 4B/lane, dst = wave-uniform base + lane*4
__device__ __forceinline__ void gl_lds4(const float* g, float* lds) {
    __builtin_amdgcn_global_load_lds(
        (const __attribute__((address_space(1))) void*)g,
        (__attribute__((address_space(3))) void*)lds, 4, 0, 0);
}

// ---- compute wave: 32 recurrence steps, pure VALU + LDS ----
template<int PHASE, bool FIRST>
__device__ __forceinline__ void compute_subtile(const float* __restrict__ yb,
                                                float* __restrict__ lt,
                                                float* __restrict__ st,
                                                float lsm, float (&buf)[SEASN],
                                                float& lev)
{
    float yp[32];                       // all 32 y-reads issued up front
    #pragma unroll
    for (int k = 0; k < 32; ++k) yp[k] = yb[k];
    #pragma unroll
    for (int k = 0; k < 32; ++k) {
        const int pos = (PHASE + k) % SEASN;      // compile-time -> buf stays in VGPRs
        const float yt = yp[k];
        if (FIRST && k == 0) {
            lev = yt * frcp(buf[0]);              // lev0 = y0 / init_seas0
            lt[0] = lev;                          // levels[:,0]
            st[0] = buf[0];                       // seasonalities col 24
        } else {
            const float sv = buf[pos];
            const float nl = lev + lsm * (yt * frcp(sv) - lev);
            const float ns = sv + lsm * (yt * frcp(nl) - sv);   // seas_sms == lev_sms (ref sic)
            lt[k] = nl; st[k] = ns;
            lev = nl; buf[pos] = ns;
        }
    }
}

__global__ __launch_bounds__(64 * (NF + 1))
void es_fwd(const float* __restrict__ y, const int* __restrict__ idxs,
            const float* __restrict__ lev_sms_p, const float* __restrict__ init_seas_p,
            float* __restrict__ levels, float* __restrict__ seasv,
            float* __restrict__ logd)
{
    __shared__ float ybuf[2][64 * YS];   // double-buffered y tiles (64 cols)
    __shared__ float ltb [2][64 * TS];   // double-buffered level sub-tiles (32 cols)
    __shared__ float stb [2][64 * TS];   // double-buffered season sub-tiles  ~65.5 KB

    const int tid   = threadIdx.x;
    const int wid   = tid >> 6;          // 0 = compute wave, 1..NF = flusher waves
    const int lane  = tid & 63;
    const int sbase = blockIdx.x * 64;

    if (wid == 0) {
        // ======================= compute wave =======================
        const int idx = idxs[sbase + lane];
        const float lsm = frcp(1.0f + __expf(-lev_sms_p[idx]));   // sigmoid
        float buf[SEASN];
        const float4* is4 = (const float4*)(init_seas_p + (size_t)idx * SEASN);
        #pragma unroll
        for (int g4 = 0; g4 < 6; ++g4) {
            float4 v = is4[g4];
            buf[4*g4+0] = __expf(v.x); buf[4*g4+1] = __expf(v.y);
            buf[4*g4+2] = __expf(v.z); buf[4*g4+3] = __expf(v.w);
        }
        #pragma unroll
        for (int j = 0; j < SEASN; ++j)          // stage init_seas for transpose-flush
            ltb[1][lane * TS + j] = buf[j];
        asm volatile("s_waitcnt lgkmcnt(0)" ::: "memory");
        __builtin_amdgcn_s_barrier();
        asm volatile("" ::: "memory");

        float lev = 1.0f;
        for (int s = 0; s < 16; ++s) {
            const float* yb = &ybuf[(s >> 1) & 1][lane * YS + (s & 1) * 32];
            float* lt = &ltb[s & 1][lane * TS];
            float* st = &stb[s & 1][lane * TS];
            lt[32] = lev;                        // entry lev for flushers' log-diff
            const int ph = s % 3;                // PHASE = (32s)%24 = 8*(s%3)
            if (s == 0)       compute_subtile<0,  true >(yb, lt, st, lsm, buf, lev);
            else if (ph == 0) compute_subtile<0,  false>(yb, lt, st, lsm, buf, lev);
            else if (ph == 1) compute_subtile<8,  false>(yb, lt, st, lsm, buf, lev);
            else              compute_subtile<16, false>(yb, lt, st, lsm, buf, lev);
            asm volatile("s_waitcnt lgkmcnt(0)" ::: "memory");   // tile visible at barrier
            __builtin_amdgcn_s_barrier();
            asm volatile("" ::: "memory");
        }
    } else {
        // ======================= flusher waves =======================
        const int f  = wid - 1;                  // 0..3: owns series rows 16f..16f+15
        const int q  = lane & 7;                 // time-quad
        const int rr = lane >> 3;                // row offset 0..7
        const int ra = 16 * f + rr;              // first owned row
        const int rb = ra + 8;                   // second owned row
        const int offa = ra * TS + 4 * q;
        const int offb = rb * TS + 4 * q;

        auto stage = [&](int T) {                // DMA 16 owned rows of y tile T
            const float* g = y + (size_t)(sbase + 16 * f) * NT + T * 64 + lane;
            float* l = &ybuf[T & 1][(16 * f) * YS];
            #pragma unroll
            for (int r = 0; r < 16; ++r)
                gl_lds4(g + (size_t)r * NT, l + r * YS);   // 256B dense per row
        };

        stage(0);
        asm volatile("s_waitcnt vmcnt(0)" ::: "memory");
        __builtin_amdgcn_s_barrier();
        asm volatile("" ::: "memory");

        // per-lane output pointers; advance 32 cols per flushed sub-tile
        float* lpa = levels + (size_t)(sbase + ra) * NT + 4 * q;
        float* lpb = levels + (size_t)(sbase + rb) * NT + 4 * q;
        float* spa = seasv  + (size_t)(sbase + ra) * SEA_STRIDE + SEASN + 4 * q;
        float* spb = seasv  + (size_t)(sbase + rb) * SEA_STRIDE + SEASN + 4 * q;
        float* dpa = logd   + (size_t)(sbase + ra) * LOG_STRIDE + 4 * q - 1;
        float* dpb = logd   + (size_t)(sbase + rb) * LOG_STRIDE + 4 * q - 1;

        auto flushrow = [&](const float* lt, const float* st, int off, int rX,
                            float* lp, float* sp, float* dp, bool guard0) {
            const float l0 = lt[off], l1 = lt[off+1], l2 = lt[off+2], l3 = lt[off+3];
            const float s0 = st[off], s1 = st[off+1], s2 = st[off+2], s3 = st[off+3];
            *(float4*)lp = make_float4(l0, l1, l2, l3);
            *(float4*)sp = make_float4(s0, s1, s2, s3);
            const float lm1 = (q == 0) ? lt[rX * TS + 32] : lt[off - 1];
            const float g0 = flog2(lm1), g1 = flog2(l0), g2 = flog2(l1),
                        g3 = flog2(l2),  g4 = flog2(l3);
            if (!(guard0 && q == 0)) dp[0] = (g1 - g0) * LN2;    // t=0 has no log-diff
            dp[1] = (g2 - g1) * LN2;
            dp[2] = (g3 - g2) * LN2;
            dp[3] = (g4 - g3) * LN2;
        };

        for (int s = 0; s < 16; ++s) {
            if (s == 0) {
                // seasv cols 0..23 = exp(init_seas) transposed (from ltb[1])
                if (q < 6) {
                    float4 va = make_float4(ltb[1][offa],   ltb[1][offa+1],
                                            ltb[1][offa+2], ltb[1][offa+3]);
                    float4 vb = make_float4(ltb[1][offb],   ltb[1][offb+1],
                                            ltb[1][offb+2], ltb[1][offb+3]);
                    *(float4*)(seasv + (size_t)(sbase + ra) * SEA_STRIDE + 4 * q) = va;
                    *(float4*)(seasv + (size_t)(sbase + rb) * SEA_STRIDE + 4 * q) = vb;
                }
            } else {
                const float* lt = ltb[(s - 1) & 1];
                const float* st = stb[(s - 1) & 1];
                const bool guard0 = (s == 1);
                flushrow(lt, st, offa, ra, lpa, spa, dpa, guard0);
                flushrow(lt, st, offb, rb, lpb, spb, dpb, guard0);
                lpa += 32; lpb += 32; spa += 32; spb += 32; dpa += 32; dpb += 32;
            }
            // stage AFTER flush so loads are the newest VMEM ops of even iters
            if (!(s & 1) && s < 14) stage((s >> 1) + 1);
            // even iters: no wait at all. odd iters: vmcnt(12) leaves only this
            // iter's 12 stores pending -> the y tile DMA'd last iter has landed.
            if (s & 1) asm volatile("s_waitcnt vmcnt(12)" ::: "memory");
            __builtin_amdgcn_s_barrier();
            asm volatile("" ::: "memory");
        }
        // epilogue: sub-tile 15 (in ltb[1]/stb[1]); pointers already at col 480
        flushrow(ltb[1], stb[1], offa, ra, lpa, spa, dpa, false);
        flushrow(ltb[1], stb[1], offb, rb, lpb, spb, dpb, false);
    }
}

extern "C" void kernel_launch(void* const* d_in, const int* in_sizes, int n_in,
                              void* d_out, int out_size, void* d_ws, size_t ws_size,
                              hipStream_t stream)
{
    const float* y         = (const float*)d_in[0];
    const int*   idxs      = (const int*)d_in[1];
    const float* lev_sms   = (const float*)d_in[2];
    // d_in[3] (seas_sms) unused: reference derives both smoothings from lev_sms_p
    const float* init_seas = (const float*)d_in[4];
    const int n_series = in_sizes[1];

    float* levels = (float*)d_out;
    float* seasv  = levels + (size_t)n_series * NT;
    float* logdv  = seasv  + (size_t)n_series * SEA_STRIDE;

    es_fwd<<<n_series / 64, 64 * (NF + 1), 0, stream>>>(y, idxs, lev_sms, init_seas,
                                                        levels, seasv, logdv);
}

// Round 3
// 307.685 us; speedup vs baseline: 1.0981x; 1.0053x over previous
//
#include <hip/hip_runtime.h>

#define NT 512
#define SEASN 24

constexpr int SEA_STRIDE = NT + SEASN;   // 536
constexpr int LOG_STRIDE = NT - 1;       // 511
constexpr float LN2 = 0.6931471805599453f;

constexpr int YS = 65;   // ybuf row stride: (65l+k)%32=(l+k)%32 -> 2-way = free
constexpr int TS = 33;   // sub-tile row stride: 32 cols + entry-lev slot

__device__ __forceinline__ float frcp(float x)  { return __builtin_amdgcn_rcpf(x); }
__device__ __forceinline__ float flog2(float x) { return __builtin_amdgcn_logf(x); }

// async global->LDS DMA: 4B/lane, dst = wave-uniform base + lane*4
__device__ __forceinline__ void gl_lds4(const float* g, float* lds) {
    __builtin_amdgcn_global_load_lds(
        (const __attribute__((address_space(1))) void*)g,
        (__attribute__((address_space(3))) void*)lds, 4, 0, 0);
}

// ---- compute wave: 32 recurrence steps, pure VALU + LDS ----
template<int PHASE, bool FIRST>
__device__ __forceinline__ void compute_subtile(const float* __restrict__ yb,
                                                float* __restrict__ lt,
                                                float* __restrict__ st,
                                                float lsm, float (&buf)[SEASN],
                                                float& lev)
{
    float yp[32];                       // all 32 y-reads issued up front
    #pragma unroll
    for (int k = 0; k < 32; ++k) yp[k] = yb[k];
    #pragma unroll
    for (int k = 0; k < 32; ++k) {
        const int pos = (PHASE + k) % SEASN;      // compile-time -> buf stays in VGPRs
        const float yt = yp[k];
        if (FIRST && k == 0) {
            lev = yt * frcp(buf[0]);              // lev0 = y0 / init_seas0
            lt[0] = lev;                          // levels[:,0]
            st[0] = buf[0];                       // seasonalities col 24
        } else {
            const float sv = buf[pos];
            const float nl = lev + lsm * (yt * frcp(sv) - lev);
            const float ns = sv + lsm * (yt * frcp(nl) - sv);   // seas_sms == lev_sms (ref sic)
            lt[k] = nl; st[k] = ns;
            lev = nl; buf[pos] = ns;
        }
    }
}

__global__ __launch_bounds__(384)
void es_fwd(const float* __restrict__ y, const int* __restrict__ idxs,
            const float* __restrict__ lev_sms_p, const float* __restrict__ init_seas_p,
            float* __restrict__ levels, float* __restrict__ seasv,
            float* __restrict__ logd)
{
    __shared__ float ybuf[2][64 * YS];   // double-buffered y tiles (64 cols)
    __shared__ float ltb [2][64 * TS];   // double-buffered level sub-tiles (32 cols)
    __shared__ float stb [2][64 * TS];   // double-buffered season sub-tiles  ~65.5 KB

    const int tid   = threadIdx.x;
    const int wid   = tid >> 6;          // 0=compute, 1=stager, 2..5=storers
    const int lane  = tid & 63;
    const int sbase = blockIdx.x * 64;

    if (wid == 0) {
        // ======================= compute wave (no VMEM after init) =======================
        const int idx = idxs[sbase + lane];
        const float lsm = frcp(1.0f + __expf(-lev_sms_p[idx]));   // sigmoid
        float buf[SEASN];
        const float4* is4 = (const float4*)(init_seas_p + (size_t)idx * SEASN);
        #pragma unroll
        for (int g4 = 0; g4 < 6; ++g4) {
            float4 v = is4[g4];
            buf[4*g4+0] = __expf(v.x); buf[4*g4+1] = __expf(v.y);
            buf[4*g4+2] = __expf(v.z); buf[4*g4+3] = __expf(v.w);
        }
        #pragma unroll
        for (int j = 0; j < SEASN; ++j)          // stage init_seas for transpose-flush
            ltb[1][lane * TS + j] = buf[j];
        asm volatile("s_waitcnt lgkmcnt(0)" ::: "memory");
        __builtin_amdgcn_s_barrier();
        asm volatile("" ::: "memory");

        float lev = 1.0f;
        for (int s = 0; s < 16; ++s) {
            const float* yb = &ybuf[(s >> 1) & 1][lane * YS + (s & 1) * 32];
            float* lt = &ltb[s & 1][lane * TS];
            float* st = &stb[s & 1][lane * TS];
            lt[32] = lev;                        // entry lev for storers' log-diff
            const int ph = s % 3;                // PHASE = (32s)%24 = 8*(s%3)
            if (s == 0)       compute_subtile<0,  true >(yb, lt, st, lsm, buf, lev);
            else if (ph == 0) compute_subtile<0,  false>(yb, lt, st, lsm, buf, lev);
            else if (ph == 1) compute_subtile<8,  false>(yb, lt, st, lsm, buf, lev);
            else              compute_subtile<16, false>(yb, lt, st, lsm, buf, lev);
            asm volatile("s_waitcnt lgkmcnt(0)" ::: "memory");   // tile visible at barrier
            __builtin_amdgcn_s_barrier();
            asm volatile("" ::: "memory");
        }
    } else if (wid == 1) {
        // ======================= stager wave (only loads on its vmcnt) ==================
        auto stage = [&](int T) {                // DMA y tile T: 64 rows x 64 cols
            const float* g = y + (size_t)sbase * NT + T * 64 + lane;
            float* l = ybuf[T & 1];
            #pragma unroll
            for (int r = 0; r < 64; ++r)
                gl_lds4(g + (size_t)r * NT, l + r * YS);   // 256B dense per row
        };
        stage(0);
        asm volatile("s_waitcnt vmcnt(0)" ::: "memory");
        __builtin_amdgcn_s_barrier();
        asm volatile("" ::: "memory");

        for (int s = 0; s < 16; ++s) {
            if (!(s & 1) && s < 14) stage((s >> 1) + 1);   // issue tile T+1 during iter 2T
            // odd iters: wait only on OUR loads, issued ~2 iterations earlier (free);
            // no stores ever enter this wave's vmcnt FIFO.
            if (s & 1) asm volatile("s_waitcnt vmcnt(0)" ::: "memory");
            __builtin_amdgcn_s_barrier();
            asm volatile("" ::: "memory");
        }
    } else {
        // ======================= storer waves (never wait on VMEM) ======================
        const int f  = wid - 2;                  // 0..3: owns series rows 16f..16f+15
        const int q  = lane & 7;                 // time-quad
        const int rr = lane >> 3;                // row offset 0..7
        const int ra = 16 * f + rr;              // first owned row
        const int rb = ra + 8;                   // second owned row
        const int offa = ra * TS + 4 * q;
        const int offb = rb * TS + 4 * q;

        // per-lane output pointers; advance 32 cols per flushed sub-tile
        float* lpa = levels + (size_t)(sbase + ra) * NT + 4 * q;
        float* lpb = levels + (size_t)(sbase + rb) * NT + 4 * q;
        float* spa = seasv  + (size_t)(sbase + ra) * SEA_STRIDE + SEASN + 4 * q;
        float* spb = seasv  + (size_t)(sbase + rb) * SEA_STRIDE + SEASN + 4 * q;
        float* dpa = logd   + (size_t)(sbase + ra) * LOG_STRIDE + 4 * q - 1;
        float* dpb = logd   + (size_t)(sbase + rb) * LOG_STRIDE + 4 * q - 1;

        auto flushrow = [&](const float* lt, const float* st, int off, int rX,
                            float* lp, float* sp, float* dp, bool guard0) {
            const float l0 = lt[off], l1 = lt[off+1], l2 = lt[off+2], l3 = lt[off+3];
            const float s0 = st[off], s1 = st[off+1], s2 = st[off+2], s3 = st[off+3];
            *(float4*)lp = make_float4(l0, l1, l2, l3);
            *(float4*)sp = make_float4(s0, s1, s2, s3);
            const float lm1 = (q == 0) ? lt[rX * TS + 32] : lt[off - 1];
            const float g0 = flog2(lm1), g1 = flog2(l0), g2 = flog2(l1),
                        g3 = flog2(l2),  g4 = flog2(l3);
            if (!(guard0 && q == 0)) dp[0] = (g1 - g0) * LN2;    // t=0 has no log-diff
            dp[1] = (g2 - g1) * LN2;
            dp[2] = (g3 - g2) * LN2;
            dp[3] = (g4 - g3) * LN2;
        };

        __builtin_amdgcn_s_barrier();
        asm volatile("" ::: "memory");

        for (int s = 0; s < 16; ++s) {
            if (s == 0) {
                // seasv cols 0..23 = exp(init_seas) transposed (from ltb[1] staging)
                if (q < 6) {
                    float4 va = make_float4(ltb[1][offa],   ltb[1][offa+1],
                                            ltb[1][offa+2], ltb[1][offa+3]);
                    float4 vb = make_float4(ltb[1][offb],   ltb[1][offb+1],
                                            ltb[1][offb+2], ltb[1][offb+3]);
                    *(float4*)(seasv + (size_t)(sbase + ra) * SEA_STRIDE + 4 * q) = va;
                    *(float4*)(seasv + (size_t)(sbase + rb) * SEA_STRIDE + 4 * q) = vb;
                }
            } else {
                const float* lt = ltb[(s - 1) & 1];
                const float* st = stb[(s - 1) & 1];
                const bool guard0 = (s == 1);
                flushrow(lt, st, offa, ra, lpa, spa, dpa, guard0);
                flushrow(lt, st, offb, rb, lpb, spb, dpb, guard0);
                lpa += 32; lpb += 32; spa += 32; spb += 32; dpa += 32; dpb += 32;
            }
            __builtin_amdgcn_s_barrier();
            asm volatile("" ::: "memory");
        }
        // epilogue: sub-tile 15 (in ltb[1]/stb[1]); pointers already at col 480
        flushrow(ltb[1], stb[1], offa, ra, lpa, spa, dpa, false);
        flushrow(ltb[1], stb[1], offb, rb, lpb, spb, dpb, false);
    }
}

extern "C" void kernel_launch(void* const* d_in, const int* in_sizes, int n_in,
                              void* d_out, int out_size, void* d_ws, size_t ws_size,
                              hipStream_t stream)
{
    const float* y         = (const float*)d_in[0];
    const int*   idxs      = (const int*)d_in[1];
    const float* lev_sms   = (const float*)d_in[2];
    // d_in[3] (seas_sms) unused: reference derives both smoothings from lev_sms_p
    const float* init_seas = (const float*)d_in[4];
    const int n_series = in_sizes[1];

    float* levels = (float*)d_out;
    float* seasv  = levels + (size_t)n_series * NT;
    float* logdv  = seasv  + (size_t)n_series * SEA_STRIDE;

    es_fwd<<<n_series / 64, 384, 0, stream>>>(y, idxs, lev_sms, init_seas,
                                              levels, seasv, logdv);
}